// Round 1
// baseline (7549.134 us; speedup 1.0000x reference)
//
#include <hip/hip_runtime.h>
#include <hip/hip_bf16.h>

#define B_DIM 16
#define S_DIM 4096
#define N_DIM 256
#define EPS 1e-5f

// ---------------------------------------------------------------------------
// Tiled f32 GEMM: Y[M,256] = X[M,256] @ W[256,256]^T + bias
// 64x64 tile, K-tile 16, 256 threads, 4x4 micro-tile.
// ---------------------------------------------------------------------------
__global__ __launch_bounds__(256)
void gemm_xwT_bias(const float* __restrict__ X,
                   const float* __restrict__ W,
                   const float* __restrict__ bias,
                   float* __restrict__ Y,
                   int M)
{
    __shared__ float Xs[16][68];   // [k][m], +4 pad keeps 16B align & breaks conflicts
    __shared__ float Ws[16][68];   // [k][n]

    const int tid = threadIdx.x;
    const int m0 = blockIdx.x * 64;
    const int n0 = blockIdx.y * 64;
    const int tx = tid & 15;       // n-direction (16)
    const int ty = tid >> 4;       // m-direction (16)

    float acc[4][4] = {};

    for (int k0 = 0; k0 < 256; k0 += 16) {
        // Stage: each thread loads one float4 of X and of W.
        // thread i -> row i/4, k-chunk (i%4)*4
        {
            const int r  = tid >> 2;
            const int kk = (tid & 3) * 4;
            float4 v = *(const float4*)(X + (size_t)(m0 + r) * 256 + k0 + kk);
            Xs[kk + 0][r] = v.x; Xs[kk + 1][r] = v.y;
            Xs[kk + 2][r] = v.z; Xs[kk + 3][r] = v.w;
            float4 w = *(const float4*)(W + (size_t)(n0 + r) * 256 + k0 + kk);
            Ws[kk + 0][r] = w.x; Ws[kk + 1][r] = w.y;
            Ws[kk + 2][r] = w.z; Ws[kk + 3][r] = w.w;
        }
        __syncthreads();

        #pragma unroll
        for (int k = 0; k < 16; ++k) {
            float4 xv = *(const float4*)&Xs[k][ty * 4];
            float4 wv = *(const float4*)&Ws[k][tx * 4];
            float xa[4] = {xv.x, xv.y, xv.z, xv.w};
            float wa[4] = {wv.x, wv.y, wv.z, wv.w};
            #pragma unroll
            for (int i = 0; i < 4; ++i)
                #pragma unroll
                for (int j = 0; j < 4; ++j)
                    acc[i][j] += xa[i] * wa[j];
        }
        __syncthreads();
    }

    // Epilogue: add bias, vectorized store.
    const int nbase = n0 + tx * 4;
    float4 bv = *(const float4*)(bias + nbase);
    #pragma unroll
    for (int i = 0; i < 4; ++i) {
        const int m = m0 + ty * 4 + i;
        float4 o;
        o.x = acc[i][0] + bv.x;
        o.y = acc[i][1] + bv.y;
        o.z = acc[i][2] + bv.z;
        o.w = acc[i][3] + bv.w;
        *(float4*)(Y + (size_t)m * 256 + nbase) = o;
    }
}

// ---------------------------------------------------------------------------
// Sequential scan: one workgroup per batch. 512 threads.
// Thread (n = t&255, q = t>>8) holds A[n, q*128 .. q*128+127] in registers.
// Per step: partial matvec, 2-way LDS reduce, +Bu, LayerNorm (wave shuffle +
// tiny LDS combine), ReLU, write state back to LDS and to global.
// ---------------------------------------------------------------------------
__global__ __launch_bounds__(512, 2)
void scan_kernel(const float* __restrict__ A,     // [256,256]
                 const float* __restrict__ Bu,    // [16,4096,256]
                 const float* __restrict__ ln_g,
                 const float* __restrict__ ln_b,
                 float* __restrict__ states)      // [16,4096,256]
{
    const int b = blockIdx.x;
    const int t = threadIdx.x;
    const int n = t & 255;
    const int q = t >> 8;          // 0 or 1

    __shared__ float s_state[256];
    __shared__ float s_partial[256];
    __shared__ float s_red[8];     // 4 wave sums + 4 wave sumsqs

    // A fragment -> registers (128 VGPRs)
    float a_reg[128];
    {
        const float* arow = A + (size_t)n * 256 + q * 128;
        #pragma unroll
        for (int i = 0; i < 32; ++i) {
            float4 v = ((const float4*)arow)[i];
            a_reg[4 * i + 0] = v.x; a_reg[4 * i + 1] = v.y;
            a_reg[4 * i + 2] = v.z; a_reg[4 * i + 3] = v.w;
        }
    }
    const float g    = ln_g[n];
    const float beta = ln_b[n];

    if (t < 256) s_state[t] = 0.0f;

    const float* bu_base  = Bu + (size_t)b * S_DIM * N_DIM;
    float*       out_base = states + (size_t)b * S_DIM * N_DIM;

    // prefetch Bu for step 0
    float bu_next = (t < 256) ? bu_base[n] : 0.0f;
    __syncthreads();

    for (int step = 0; step < S_DIM; ++step) {
        // --- partial matvec over this thread's half of K ---
        float acc = 0.0f;
        const float4* sp = (const float4*)(s_state + q * 128);
        #pragma unroll
        for (int i = 0; i < 32; ++i) {
            float4 v = sp[i];
            acc += a_reg[4 * i + 0] * v.x;
            acc += a_reg[4 * i + 1] * v.y;
            acc += a_reg[4 * i + 2] * v.z;
            acc += a_reg[4 * i + 3] * v.w;
        }
        const float bu_cur = bu_next;
        if (step + 1 < S_DIM && t < 256)
            bu_next = bu_base[(size_t)(step + 1) * N_DIM + n];

        if (q == 1) s_partial[n] = acc;
        __syncthreads();

        float s_val = 0.0f, sum = 0.0f, sumsq = 0.0f;
        if (q == 0) {
            s_val = acc + s_partial[n] + bu_cur;
            sum   = s_val;
            sumsq = s_val * s_val;
            #pragma unroll
            for (int off = 1; off < 64; off <<= 1) {
                sum   += __shfl_xor(sum, off, 64);
                sumsq += __shfl_xor(sumsq, off, 64);
            }
            if ((n & 63) == 0) {
                s_red[n >> 6]       = sum;
                s_red[4 + (n >> 6)] = sumsq;
            }
        }
        __syncthreads();

        if (q == 0) {
            float tot = 0.0f, tot2 = 0.0f;
            #pragma unroll
            for (int w = 0; w < 4; ++w) { tot += s_red[w]; tot2 += s_red[4 + w]; }
            const float mu  = tot * (1.0f / 256.0f);
            const float var = tot2 * (1.0f / 256.0f) - mu * mu;
            const float inv = rsqrtf(var + EPS);
            float y = (s_val - mu) * inv * g + beta;
            y = fmaxf(y, 0.0f);
            s_state[n] = y;
            out_base[(size_t)step * N_DIM + n] = y;
        }
        __syncthreads();
    }
}

// ---------------------------------------------------------------------------
extern "C" void kernel_launch(void* const* d_in, const int* in_sizes, int n_in,
                              void* d_out, int out_size, void* d_ws, size_t ws_size,
                              hipStream_t stream)
{
    const float* u    = (const float*)d_in[0];   // [16,4096,256]
    const float* A    = (const float*)d_in[1];   // [256,256]
    const float* B_w  = (const float*)d_in[2];   // [256,256]
    const float* B_b  = (const float*)d_in[3];   // [256]
    const float* ln_g = (const float*)d_in[4];   // [256]
    const float* ln_b = (const float*)d_in[5];   // [256]
    const float* C_w  = (const float*)d_in[6];   // [256,256]
    const float* C_b  = (const float*)d_in[7];   // [256]

    float* states  = (float*)d_out;                          // first 16M floats
    float* outputs = (float*)d_out + (size_t)B_DIM * S_DIM * N_DIM;  // second 16M

    // Stage Bu in the outputs region (dead until kernel 3 overwrites it).
    float* Bu = outputs;

    const int M = B_DIM * S_DIM;   // 65536

    // 1) Bu = u @ B_w^T + B_b
    {
        dim3 grid(M / 64, N_DIM / 64);
        hipLaunchKernelGGL(gemm_xwT_bias, grid, dim3(256), 0, stream,
                           u, B_w, B_b, Bu, M);
    }

    // 2) sequential scan -> states
    {
        hipLaunchKernelGGL(scan_kernel, dim3(B_DIM), dim3(512), 0, stream,
                           A, Bu, ln_g, ln_b, states);
    }

    // 3) outputs = states @ C_w^T + C_b   (overwrites the Bu staging area)
    {
        dim3 grid(M / 64, N_DIM / 64);
        hipLaunchKernelGGL(gemm_xwT_bias, grid, dim3(256), 0, stream,
                           states, C_w, C_b, outputs, M);
    }
}

// Round 2
// 6773.584 us; speedup vs baseline: 1.1145x; 1.1145x over previous
//
#include <hip/hip_runtime.h>
#include <hip/hip_bf16.h>

#define B_DIM 16
#define S_DIM 4096
#define N_DIM 256
#define EPS 1e-5f

// ---------------------------------------------------------------------------
// Tiled f32 GEMM: Y[M,256] = X[M,256] @ W[256,256]^T + bias
// 64x64 tile, K-tile 16, 256 threads, 4x4 micro-tile.
// ---------------------------------------------------------------------------
__global__ __launch_bounds__(256)
void gemm_xwT_bias(const float* __restrict__ X,
                   const float* __restrict__ W,
                   const float* __restrict__ bias,
                   float* __restrict__ Y,
                   int M)
{
    __shared__ float Xs[16][68];
    __shared__ float Ws[16][68];

    const int tid = threadIdx.x;
    const int m0 = blockIdx.x * 64;
    const int n0 = blockIdx.y * 64;
    const int tx = tid & 15;
    const int ty = tid >> 4;

    float acc[4][4] = {};

    for (int k0 = 0; k0 < 256; k0 += 16) {
        {
            const int r  = tid >> 2;
            const int kk = (tid & 3) * 4;
            float4 v = *(const float4*)(X + (size_t)(m0 + r) * 256 + k0 + kk);
            Xs[kk + 0][r] = v.x; Xs[kk + 1][r] = v.y;
            Xs[kk + 2][r] = v.z; Xs[kk + 3][r] = v.w;
            float4 w = *(const float4*)(W + (size_t)(n0 + r) * 256 + k0 + kk);
            Ws[kk + 0][r] = w.x; Ws[kk + 1][r] = w.y;
            Ws[kk + 2][r] = w.z; Ws[kk + 3][r] = w.w;
        }
        __syncthreads();

        #pragma unroll
        for (int k = 0; k < 16; ++k) {
            float4 xv = *(const float4*)&Xs[k][ty * 4];
            float4 wv = *(const float4*)&Ws[k][tx * 4];
            float xa[4] = {xv.x, xv.y, xv.z, xv.w};
            float wa[4] = {wv.x, wv.y, wv.z, wv.w};
            #pragma unroll
            for (int i = 0; i < 4; ++i)
                #pragma unroll
                for (int j = 0; j < 4; ++j)
                    acc[i][j] += xa[i] * wa[j];
        }
        __syncthreads();
    }

    const int nbase = n0 + tx * 4;
    float4 bv = *(const float4*)(bias + nbase);
    #pragma unroll
    for (int i = 0; i < 4; ++i) {
        const int m = m0 + ty * 4 + i;
        float4 o;
        o.x = acc[i][0] + bv.x;
        o.y = acc[i][1] + bv.y;
        o.z = acc[i][2] + bv.z;
        o.w = acc[i][3] + bv.w;
        *(float4*)(Y + (size_t)m * 256 + nbase) = o;
    }
}

// ---------------------------------------------------------------------------
// Sequential scan, v2: one workgroup (256 threads) per batch.
// Thread t: f = t>>6 (K-quarter), o4 = (t&63)*4 (4 output rows).
// A fragment A[o4..o4+3][64f..64f+64) lives in 256 VGPRs (a4[4][16] float4).
// Per step:
//   - each wave reads its 64-float state slice from LDS (16 uniform b128)
//   - 256 FMA-instructions -> 4 partial dots
//   - b128 partial write, barrier
//   - 4-way partial reduce + Bu, wave-shuffle LN stats, barrier
//   - y = relu(LN(v)), write to LDS state + global, barrier
// ---------------------------------------------------------------------------
__global__ __launch_bounds__(256, 1)
void scan_kernel(const float* __restrict__ A,     // [256,256]
                 const float* __restrict__ Bu,    // [16,4096,256]
                 const float* __restrict__ ln_g,
                 const float* __restrict__ ln_b,
                 float* __restrict__ states)      // [16,4096,256]
{
    const int b = blockIdx.x;
    const int t = threadIdx.x;
    const int f  = t >> 6;          // K-quarter 0..3
    const int o4 = (t & 63) * 4;    // first of 4 output rows
    const int lane = t & 63;
    const int w = t >> 6;           // wave id == f

    __shared__ float s_state[256];
    __shared__ float s_partial[4 * 256];
    __shared__ float s_redA[4];
    __shared__ float s_redB[4];

    // --- load A fragment into registers: a4[r][c] = A[o4+r][64f + 4c .. +4)
    float4 a4[4][16];
    #pragma unroll
    for (int r = 0; r < 4; ++r) {
        const float* arow = A + (size_t)(o4 + r) * 256 + f * 64;
        #pragma unroll
        for (int c = 0; c < 16; ++c)
            a4[r][c] = ((const float4*)arow)[c];
    }

    const float g    = ln_g[t];
    const float beta = ln_b[t];

    s_state[t] = 0.0f;

    const float* bu_base  = Bu + (size_t)b * S_DIM * N_DIM;
    float*       out_base = states + (size_t)b * S_DIM * N_DIM;

    // 2-deep Bu prefetch pipeline
    float bu0 = bu_base[t];
    float bu1 = bu_base[N_DIM + t];
    __syncthreads();

    for (int step = 0; step < S_DIM; ++step) {
        // issue prefetch for step+2 early
        float bu2 = 0.0f;
        if (step + 2 < S_DIM)
            bu2 = bu_base[(size_t)(step + 2) * N_DIM + t];

        // --- partial matvec over this wave's K-quarter (uniform LDS reads) ---
        float acc0 = 0.0f, acc1 = 0.0f, acc2 = 0.0f, acc3 = 0.0f;
        const float4* sp = (const float4*)(s_state + f * 64);
        #pragma unroll
        for (int c = 0; c < 16; ++c) {
            float4 s4 = sp[c];
            float4 a0 = a4[0][c], a1 = a4[1][c], a2 = a4[2][c], a3 = a4[3][c];
            acc0 += a0.x * s4.x + a0.y * s4.y + a0.z * s4.z + a0.w * s4.w;
            acc1 += a1.x * s4.x + a1.y * s4.y + a1.z * s4.z + a1.w * s4.w;
            acc2 += a2.x * s4.x + a2.y * s4.y + a2.z * s4.z + a2.w * s4.w;
            acc3 += a3.x * s4.x + a3.y * s4.y + a3.z * s4.z + a3.w * s4.w;
        }
        *(float4*)&s_partial[f * 256 + o4] = make_float4(acc0, acc1, acc2, acc3);
        __syncthreads();

        // --- reduce 4 K-partials for output n = t, add Bu ---
        float v = s_partial[t] + s_partial[256 + t]
                + s_partial[512 + t] + s_partial[768 + t] + bu0;

        // --- LN stats across 256 values: wave shuffle + tiny LDS combine ---
        float sum = v, sumsq = v * v;
        #pragma unroll
        for (int off = 1; off < 64; off <<= 1) {
            sum   += __shfl_xor(sum, off, 64);
            sumsq += __shfl_xor(sumsq, off, 64);
        }
        if (lane == 0) { s_redA[w] = sum; s_redB[w] = sumsq; }
        __syncthreads();

        const float tot  = s_redA[0] + s_redA[1] + s_redA[2] + s_redA[3];
        const float tot2 = s_redB[0] + s_redB[1] + s_redB[2] + s_redB[3];
        const float mu  = tot * (1.0f / 256.0f);
        const float var = tot2 * (1.0f / 256.0f) - mu * mu;
        const float inv = rsqrtf(var + EPS);
        float y = (v - mu) * inv * g + beta;
        y = fmaxf(y, 0.0f);

        s_state[t] = y;
        out_base[(size_t)step * N_DIM + t] = y;

        bu0 = bu1;
        bu1 = bu2;
        __syncthreads();
    }
}

// ---------------------------------------------------------------------------
extern "C" void kernel_launch(void* const* d_in, const int* in_sizes, int n_in,
                              void* d_out, int out_size, void* d_ws, size_t ws_size,
                              hipStream_t stream)
{
    const float* u    = (const float*)d_in[0];   // [16,4096,256]
    const float* A    = (const float*)d_in[1];   // [256,256]
    const float* B_w  = (const float*)d_in[2];   // [256,256]
    const float* B_b  = (const float*)d_in[3];   // [256]
    const float* ln_g = (const float*)d_in[4];   // [256]
    const float* ln_b = (const float*)d_in[5];   // [256]
    const float* C_w  = (const float*)d_in[6];   // [256,256]
    const float* C_b  = (const float*)d_in[7];   // [256]

    float* states  = (float*)d_out;
    float* outputs = (float*)d_out + (size_t)B_DIM * S_DIM * N_DIM;

    // Stage Bu in the outputs region (dead until kernel 3 overwrites it).
    float* Bu = outputs;

    const int M = B_DIM * S_DIM;   // 65536

    // 1) Bu = u @ B_w^T + B_b
    {
        dim3 grid(M / 64, N_DIM / 64);
        hipLaunchKernelGGL(gemm_xwT_bias, grid, dim3(256), 0, stream,
                           u, B_w, B_b, Bu, M);
    }

    // 2) sequential scan -> states
    {
        hipLaunchKernelGGL(scan_kernel, dim3(B_DIM), dim3(256), 0, stream,
                           A, Bu, ln_g, ln_b, states);
    }

    // 3) outputs = states @ C_w^T + C_b   (overwrites the Bu staging area)
    {
        dim3 grid(M / 64, N_DIM / 64);
        hipLaunchKernelGGL(gemm_xwT_bias, grid, dim3(256), 0, stream,
                           states, C_w, C_b, outputs, M);
    }
}

// Round 3
// 3999.522 us; speedup vs baseline: 1.8875x; 1.6936x over previous
//
#include <hip/hip_runtime.h>
#include <hip/hip_bf16.h>

#define B_DIM 16
#define S_DIM 4096
#define N_DIM 256
#define EPS 1e-5f

// ---------------------------------------------------------------------------
// Tiled f32 GEMM: Y[M,256] = X[M,256] @ W[256,256]^T + bias
// ---------------------------------------------------------------------------
__global__ __launch_bounds__(256)
void gemm_xwT_bias(const float* __restrict__ X,
                   const float* __restrict__ W,
                   const float* __restrict__ bias,
                   float* __restrict__ Y,
                   int M)
{
    __shared__ float Xs[16][68];
    __shared__ float Ws[16][68];

    const int tid = threadIdx.x;
    const int m0 = blockIdx.x * 64;
    const int n0 = blockIdx.y * 64;
    const int tx = tid & 15;
    const int ty = tid >> 4;

    float acc[4][4] = {};

    for (int k0 = 0; k0 < 256; k0 += 16) {
        {
            const int r  = tid >> 2;
            const int kk = (tid & 3) * 4;
            float4 v = *(const float4*)(X + (size_t)(m0 + r) * 256 + k0 + kk);
            Xs[kk + 0][r] = v.x; Xs[kk + 1][r] = v.y;
            Xs[kk + 2][r] = v.z; Xs[kk + 3][r] = v.w;
            float4 w = *(const float4*)(W + (size_t)(n0 + r) * 256 + k0 + kk);
            Ws[kk + 0][r] = w.x; Ws[kk + 1][r] = w.y;
            Ws[kk + 2][r] = w.z; Ws[kk + 3][r] = w.w;
        }
        __syncthreads();

        #pragma unroll
        for (int k = 0; k < 16; ++k) {
            float4 xv = *(const float4*)&Xs[k][ty * 4];
            float4 wv = *(const float4*)&Ws[k][tx * 4];
            float xa[4] = {xv.x, xv.y, xv.z, xv.w};
            float wa[4] = {wv.x, wv.y, wv.z, wv.w};
            #pragma unroll
            for (int i = 0; i < 4; ++i)
                #pragma unroll
                for (int j = 0; j < 4; ++j)
                    acc[i][j] += xa[i] * wa[j];
        }
        __syncthreads();
    }

    const int nbase = n0 + tx * 4;
    float4 bv = *(const float4*)(bias + nbase);
    #pragma unroll
    for (int i = 0; i < 4; ++i) {
        const int m = m0 + ty * 4 + i;
        float4 o;
        o.x = acc[i][0] + bv.x;
        o.y = acc[i][1] + bv.y;
        o.z = acc[i][2] + bv.z;
        o.w = acc[i][3] + bv.w;
        *(float4*)(Y + (size_t)m * 256 + nbase) = o;
    }
}

// ---------------------------------------------------------------------------
// DPP helper: one term of the canonical wave64 reduction. VALU pipe, no LDS.
// ---------------------------------------------------------------------------
template<int CTRL>
__device__ __forceinline__ float dpp_term(float x) {
    return __int_as_float(
        __builtin_amdgcn_update_dpp(0, __float_as_int(x), CTRL, 0xF, 0xF, true));
}

// Full-wave (64-lane) sum; result valid in lane 63 only.
__device__ __forceinline__ float wave_sum_l63(float v) {
    v += dpp_term<0x111>(v);   // row_shr:1
    v += dpp_term<0x112>(v);   // row_shr:2
    v += dpp_term<0x114>(v);   // row_shr:4
    v += dpp_term<0x118>(v);   // row_shr:8
    v += dpp_term<0x142>(v);   // row_bcast:15
    v += dpp_term<0x143>(v);   // row_bcast:31
    return v;
}

// ---------------------------------------------------------------------------
// Sequential scan, v3: one workgroup (512 threads, 8 waves) per batch.
// Thread t: og = t&31, kg = t>>5 (0..15).
//   A fragment: rows {32r+og, r=0..7} x cols [16*kg, 16*kg+16) = 128 floats,
//   held in 32 float4 VGPRs (no spill: ~185 VGPR total < 256 cap at 2 w/SIMD).
// Per step:
//   ph1: read 16-float state slice (4 x b128 broadcast, conflict-free),
//        128 FMAs -> 8 partial dots, write partials [r][kg][og] (stride-1).
//   ph2: owners (t<256) sum 16 partials + Bu, DPP-reduce LN stats (VALU pipe).
//   ph3: owners finish LN, ReLU, write state to LDS + global.
// 3 barriers/step.
// ---------------------------------------------------------------------------
__global__ __launch_bounds__(512, 2)
void scan_kernel(const float* __restrict__ A,     // [256,256]
                 const float* __restrict__ Bu,    // [16,4096,256]
                 const float* __restrict__ ln_g,
                 const float* __restrict__ ln_b,
                 float* __restrict__ states)      // [16,4096,256]
{
    const int b    = blockIdx.x;
    const int t    = threadIdx.x;
    const int lane = t & 63;
    const int w    = t >> 6;      // wave 0..7
    const int og   = t & 31;      // output sub-index
    const int kg   = t >> 5;      // K-group 0..15 (uniform per half-wave)

    __shared__ float s_state[256];
    __shared__ float s_partial[8 * 512];   // [r][kg][og] -> r*512 + kg*32 + og
    __shared__ float s_redA[4];
    __shared__ float s_redB[4];

    // --- A fragment -> 128 VGPRs
    float4 a4[8][4];
    #pragma unroll
    for (int r = 0; r < 8; ++r) {
        const float* arow = A + (size_t)(32 * r + og) * 256 + kg * 16;
        #pragma unroll
        for (int c = 0; c < 4; ++c)
            a4[r][c] = ((const float4*)arow)[c];
    }

    const bool owner = (t < 256);
    float g = 0.0f, beta = 0.0f;
    if (owner) { g = ln_g[t]; beta = ln_b[t]; }

    if (owner) s_state[t] = 0.0f;

    const float* bu_base  = Bu + (size_t)b * S_DIM * N_DIM;
    float*       out_base = states + (size_t)b * S_DIM * N_DIM;

    float bu0 = 0.0f, bu1 = 0.0f;
    if (owner) {
        bu0 = bu_base[t];
        bu1 = bu_base[N_DIM + t];
    }
    __syncthreads();

    for (int step = 0; step < S_DIM; ++step) {
        // prefetch Bu for step+2 (latency hidden under the FMA block)
        float bu2 = 0.0f;
        if (owner && step + 2 < S_DIM)
            bu2 = bu_base[(size_t)(step + 2) * N_DIM + t];

        // --- ph1: partial matvec over this thread's 16-col slice ---
        const float4* sp = (const float4*)(s_state + kg * 16);
        float4 s0 = sp[0], s1 = sp[1], s2 = sp[2], s3 = sp[3];
        float acc[8];
        #pragma unroll
        for (int r = 0; r < 8; ++r) {
            float4 a0 = a4[r][0], a1 = a4[r][1], a2 = a4[r][2], a3 = a4[r][3];
            float x;
            x  = a0.x * s0.x + a0.y * s0.y + a0.z * s0.z + a0.w * s0.w;
            x += a1.x * s1.x + a1.y * s1.y + a1.z * s1.z + a1.w * s1.w;
            x += a2.x * s2.x + a2.y * s2.y + a2.z * s2.z + a2.w * s2.w;
            x += a3.x * s3.x + a3.y * s3.y + a3.z * s3.z + a3.w * s3.w;
            acc[r] = x;
        }
        #pragma unroll
        for (int r = 0; r < 8; ++r)
            s_partial[r * 512 + kg * 32 + og] = acc[r];
        __syncthreads();

        // --- ph2: owners reduce 16 K-partials, add Bu, DPP LN stats ---
        float v = 0.0f;
        if (owner) {
            const int base = (t >> 5) * 512 + (t & 31);
            float x0 = s_partial[base +  0 * 32], x1 = s_partial[base +  1 * 32];
            float x2 = s_partial[base +  2 * 32], x3 = s_partial[base +  3 * 32];
            float x4 = s_partial[base +  4 * 32], x5 = s_partial[base +  5 * 32];
            float x6 = s_partial[base +  6 * 32], x7 = s_partial[base +  7 * 32];
            float x8 = s_partial[base +  8 * 32], x9 = s_partial[base +  9 * 32];
            float xa = s_partial[base + 10 * 32], xb = s_partial[base + 11 * 32];
            float xc = s_partial[base + 12 * 32], xd = s_partial[base + 13 * 32];
            float xe = s_partial[base + 14 * 32], xf = s_partial[base + 15 * 32];
            v = (((x0 + x1) + (x2 + x3)) + ((x4 + x5) + (x6 + x7)))
              + (((x8 + x9) + (xa + xb)) + ((xc + xd) + (xe + xf))) + bu0;

            float sum   = wave_sum_l63(v);
            float sumsq = wave_sum_l63(v * v);
            if (lane == 63) { s_redA[w] = sum; s_redB[w] = sumsq; }
        }
        __syncthreads();

        // --- ph3: owners normalize, ReLU, write state ---
        if (owner) {
            const float tot  = (s_redA[0] + s_redA[1]) + (s_redA[2] + s_redA[3]);
            const float tot2 = (s_redB[0] + s_redB[1]) + (s_redB[2] + s_redB[3]);
            const float mu  = tot * (1.0f / 256.0f);
            const float var = tot2 * (1.0f / 256.0f) - mu * mu;
            const float inv = rsqrtf(var + EPS);
            float y = (v - mu) * inv * g + beta;
            y = fmaxf(y, 0.0f);
            s_state[t] = y;
            out_base[(size_t)step * N_DIM + t] = y;
            bu0 = bu1;
            bu1 = bu2;
        }
        __syncthreads();
    }
}

// ---------------------------------------------------------------------------
extern "C" void kernel_launch(void* const* d_in, const int* in_sizes, int n_in,
                              void* d_out, int out_size, void* d_ws, size_t ws_size,
                              hipStream_t stream)
{
    const float* u    = (const float*)d_in[0];
    const float* A    = (const float*)d_in[1];
    const float* B_w  = (const float*)d_in[2];
    const float* B_b  = (const float*)d_in[3];
    const float* ln_g = (const float*)d_in[4];
    const float* ln_b = (const float*)d_in[5];
    const float* C_w  = (const float*)d_in[6];
    const float* C_b  = (const float*)d_in[7];

    float* states  = (float*)d_out;
    float* outputs = (float*)d_out + (size_t)B_DIM * S_DIM * N_DIM;

    // Stage Bu in the outputs region (dead until kernel 3 overwrites it).
    float* Bu = outputs;

    const int M = B_DIM * S_DIM;   // 65536

    // 1) Bu = u @ B_w^T + B_b
    {
        dim3 grid(M / 64, N_DIM / 64);
        hipLaunchKernelGGL(gemm_xwT_bias, grid, dim3(256), 0, stream,
                           u, B_w, B_b, Bu, M);
    }

    // 2) sequential scan -> states
    {
        hipLaunchKernelGGL(scan_kernel, dim3(B_DIM), dim3(512), 0, stream,
                           A, Bu, ln_g, ln_b, states);
    }

    // 3) outputs = states @ C_w^T + C_b
    {
        dim3 grid(M / 64, N_DIM / 64);
        hipLaunchKernelGGL(gemm_xwT_bias, grid, dim3(256), 0, stream,
                           states, C_w, C_b, outputs, M);
    }
}